// Round 3
// baseline (735.884 us; speedup 1.0000x reference)
//
#include <hip/hip_runtime.h>
#include <math.h>

#define T_DIM 2048
#define F_DIM 513
#define N_ITER 10

// ws float offsets
#define OFF_W    0        // 513*36*2 = 36936 floats (complex W[f][k][m])
#define OFF_WT   36936    // 6*2048   = 12288 floats
#define OFF_P0   49224    // 513*2 partial pairs (parity 0)
#define OFF_P1   50250    // 513*2 partial pairs (parity 1)

// -------- transpose X (K,T,F) -> Xt (F,K,T), + init W=I and partial buffers --------
__global__ __launch_bounds__(256) void transp(const float2* __restrict__ X,
                                              float2* __restrict__ Xt,
                                              float* __restrict__ ws) {
    const int fb  = blockIdx.x + 64 * (blockIdx.y + 17 * blockIdx.z);
    const int tid = threadIdx.x;
    if (fb < 73) {
        int idx = fb * 256 + tid;              // entry index into W (F*36 = 18468)
        if (idx < F_DIM * 36) {
            int e = idx % 36;
            ws[OFF_W + 2 * idx]     = ((e / 6) == (e % 6)) ? 1.0f : 0.0f;
            ws[OFF_W + 2 * idx + 1] = 0.0f;
        }
    } else if (fb < 78) {
        int idx = (fb - 73) * 256 + tid;       // 2*513 = 1026 floats each buffer
        if (idx < 2 * F_DIM) { ws[OFF_P0 + idx] = 1.0f; ws[OFF_P1 + idx] = 1.0f; }
    }

    __shared__ float2 tile[32][33];
    const int k  = blockIdx.z;
    const int t0 = blockIdx.x * 32;
    const int f0 = blockIdx.y * 32;
    const int tx = tid & 31, ty = tid >> 5;    // tx 0..31, ty 0..7
#pragma unroll
    for (int j = 0; j < 4; ++j) {
        int t = t0 + ty + j * 8;
        int f = f0 + tx;
        if (f < F_DIM) tile[ty + j * 8][tx] = X[((size_t)k * T_DIM + t) * F_DIM + f];
    }
    __syncthreads();
#pragma unroll
    for (int j = 0; j < 4; ++j) {
        int f = f0 + ty + j * 8;
        int t = t0 + tx;
        if (f < F_DIM) Xt[((size_t)f * 6 + k) * T_DIM + t] = tile[tx][ty + j * 8];
    }
}

// -------- pass A: wt[k,t] = 1/clip(sqrt(clip(sum_f |(W X)|^2))) --------
__global__ __launch_bounds__(512) void passA(const float2* __restrict__ X,
                                             float* __restrict__ ws,
                                             const float* __restrict__ pin) {
    __shared__ float sred[384];
    const int tid = threadIdx.x, wave = tid >> 6, lane = tid & 63;

    // convergence check from previous iteration's partials (redundant per block)
    {
        float d2 = 0.f, o2 = 0.f;
        for (int i = tid; i < F_DIM; i += 512) { d2 += pin[2 * i]; o2 += pin[2 * i + 1]; }
#pragma unroll
        for (int d = 1; d < 64; d <<= 1) { d2 += __shfl_xor(d2, d); o2 += __shfl_xor(o2, d); }
        if (lane == 0) { sred[wave * 2] = d2; sred[wave * 2 + 1] = o2; }
        __syncthreads();
        d2 = 0.f; o2 = 0.f;
#pragma unroll
        for (int w = 0; w < 8; ++w) { d2 += sred[w * 2]; o2 += sred[w * 2 + 1]; }
        float rel = sqrtf(d2) / fmaxf(sqrtf(o2), 1.1920929e-07f);
        __syncthreads();
        if (rel < 1e-5f) return;
    }

    const float2* Wc = (const float2*)(ws + OFF_W);
    float* wt = ws + OFF_WT;
    const int t0 = blockIdx.x * 8;

    float s[48];
#pragma unroll
    for (int i = 0; i < 48; ++i) s[i] = 0.0f;

    for (int f = tid; f < F_DIM; f += 512) {
        float2 w[36];
#pragma unroll
        for (int i = 0; i < 36; ++i) w[i] = Wc[f * 36 + i];
#pragma unroll
        for (int tl = 0; tl < 8; ++tl) {
            int t = t0 + tl;
            float2 x[6];
#pragma unroll
            for (int m = 0; m < 6; ++m) x[m] = X[((size_t)m * T_DIM + t) * F_DIM + f];
#pragma unroll
            for (int k = 0; k < 6; ++k) {
                float yr = 0.f, yi = 0.f;
#pragma unroll
                for (int m = 0; m < 6; ++m) {
                    float2 wk = w[k * 6 + m];
                    yr += wk.x * x[m].x - wk.y * x[m].y;
                    yi += wk.x * x[m].y + wk.y * x[m].x;
                }
                s[k * 8 + tl] += yr * yr + yi * yi;
            }
        }
    }
#pragma unroll
    for (int i = 0; i < 48; ++i) {
        float v = s[i];
#pragma unroll
        for (int d = 1; d < 64; d <<= 1) v += __shfl_xor(v, d);
        s[i] = v;
    }
    if (lane == 0) {
#pragma unroll
        for (int i = 0; i < 48; ++i) sred[wave * 48 + i] = s[i];
    }
    __syncthreads();
    if (tid < 48) {
        float r2 = 0.f;
#pragma unroll
        for (int w = 0; w < 8; ++w) r2 += sred[w * 48 + tid];
        int k = tid >> 3, tl = tid & 7;
        float r = sqrtf(fmaxf(r2, 1e-10f));
        wt[k * T_DIM + t0 + tl] = 1.0f / fmaxf(r, 1e-10f);
    }
}

// -------- pass B+C: V[f] in LDS, ISS update of W[f], write diff partials --------
__global__ __launch_bounds__(128) void passBC(const float2* __restrict__ Xt,
                                              float* __restrict__ ws,
                                              const float* __restrict__ pin,
                                              float* __restrict__ pout) {
    __shared__ float red[2 * 108 * 17];   // per-wave quad-group partials
    __shared__ float VL[432];             // V[6][6][6] complex
    __shared__ float WL[72];              // W[f] rows, complex
    __shared__ float sc[4];
    const int bid = blockIdx.x;
    const int tid = threadIdx.x, wv = tid >> 6, lane = tid & 63;

    // convergence check
    {
        float d2 = 0.f, o2 = 0.f;
        for (int i = tid; i < F_DIM; i += 128) { d2 += pin[2 * i]; o2 += pin[2 * i + 1]; }
#pragma unroll
        for (int d = 1; d < 64; d <<= 1) { d2 += __shfl_xor(d2, d); o2 += __shfl_xor(o2, d); }
        if (lane == 0) { sc[wv * 2] = d2; sc[wv * 2 + 1] = o2; }
        __syncthreads();
        d2 = sc[0] + sc[2]; o2 = sc[1] + sc[3];
        float rel = sqrtf(d2) / fmaxf(sqrtf(o2), 1.1920929e-07f);
        __syncthreads();
        if (rel < 1e-5f) {
            if (tid == 0) { pout[2 * bid] = 0.0f; pout[2 * bid + 1] = 1.0f; }
            return;
        }
    }

    const int f = bid;
    // ---- accumulate weighted covariances: wave wv handles k = 3*wv + j ----
    float accd[3][6], accr[3][15], acci[3][15];
#pragma unroll
    for (int j = 0; j < 3; ++j) {
#pragma unroll
        for (int a = 0; a < 6; ++a) accd[j][a] = 0.f;
#pragma unroll
        for (int p = 0; p < 15; ++p) { accr[j][p] = 0.f; acci[j][p] = 0.f; }
    }
    const float2* xb = Xt + (size_t)f * 6 * T_DIM;
    const float* wt0 = ws + OFF_WT + (3 * wv) * T_DIM;
    for (int t = lane; t < T_DIM; t += 64) {
        float g0 = wt0[t], g1 = wt0[T_DIM + t], g2 = wt0[2 * T_DIM + t];
        float2 x[6];
#pragma unroll
        for (int m = 0; m < 6; ++m) x[m] = xb[(size_t)m * T_DIM + t];
        float od[6];
#pragma unroll
        for (int a = 0; a < 6; ++a) od[a] = x[a].x * x[a].x + x[a].y * x[a].y;
        float opr[15], opi[15];
#pragma unroll
        for (int a = 1; a < 6; ++a)
#pragma unroll
            for (int b = 0; b < a; ++b) {
                const int p = a * (a - 1) / 2 + b;
                opr[p] = x[a].x * x[b].x + x[a].y * x[b].y;
                opi[p] = x[a].y * x[b].x - x[a].x * x[b].y;
            }
#pragma unroll
        for (int a = 0; a < 6; ++a) {
            accd[0][a] += g0 * od[a];
            accd[1][a] += g1 * od[a];
            accd[2][a] += g2 * od[a];
        }
#pragma unroll
        for (int p = 0; p < 15; ++p) {
            accr[0][p] += g0 * opr[p]; acci[0][p] += g0 * opi[p];
            accr[1][p] += g1 * opr[p]; acci[1][p] += g1 * opi[p];
            accr[2][p] += g2 * opr[p]; acci[2][p] += g2 * opi[p];
        }
    }
    // 4-lane pre-reduce, 16 group slots per value, per wave
#pragma unroll
    for (int j = 0; j < 3; ++j) {
#pragma unroll
        for (int a = 0; a < 6; ++a) {
            float v = accd[j][a];
            v += __shfl_xor(v, 1); v += __shfl_xor(v, 2);
            if ((lane & 3) == 0) red[(wv * 108 + j * 36 + a) * 17 + (lane >> 2)] = v;
        }
#pragma unroll
        for (int p = 0; p < 15; ++p) {
            float vr = accr[j][p];
            vr += __shfl_xor(vr, 1); vr += __shfl_xor(vr, 2);
            float vi = acci[j][p];
            vi += __shfl_xor(vi, 1); vi += __shfl_xor(vi, 2);
            if ((lane & 3) == 0) {
                red[(wv * 108 + j * 36 + 6 + p) * 17 + (lane >> 2)]  = vr;
                red[(wv * 108 + j * 36 + 21 + p) * 17 + (lane >> 2)] = vi;
            }
        }
    }
    __syncthreads();
    for (int v = tid; v < 216; v += 128) {
        float sum = 0.f;
#pragma unroll
        for (int i = 0; i < 16; ++i) sum += red[v * 17 + i];
        sum *= (1.0f / (float)T_DIM);
        int w = v / 108, rem = v % 108;
        int j = rem / 36, e = rem % 36;
        int k = 3 * w + j;
        if (e < 6) {
            VL[((k * 6 + e) * 6 + e) * 2]     = sum + 1e-6f;
            VL[((k * 6 + e) * 6 + e) * 2 + 1] = 0.f;
        } else if (e < 21) {
            int p = e - 6;
            int a = (p < 1) ? 1 : (p < 3) ? 2 : (p < 6) ? 3 : (p < 10) ? 4 : 5;
            int b = p - a * (a - 1) / 2;
            VL[((k * 6 + a) * 6 + b) * 2] = sum;
            VL[((k * 6 + b) * 6 + a) * 2] = sum;
        } else {
            int p = e - 21;
            int a = (p < 1) ? 1 : (p < 3) ? 2 : (p < 6) ? 3 : (p < 10) ? 4 : 5;
            int b = p - a * (a - 1) / 2;
            VL[((k * 6 + a) * 6 + b) * 2 + 1] =  sum;
            VL[((k * 6 + b) * 6 + a) * 2 + 1] = -sum;
        }
    }
    __syncthreads();

    // ---- ISS update: threads 0..5 own row m of W[f] ----
    float vm[36][2];
    float w6[6][2], wold[6][2];
    const int m = tid;
    if (tid < 6) {
#pragma unroll
        for (int i = 0; i < 36; ++i) {
            vm[i][0] = VL[(m * 36 + i) * 2];
            vm[i][1] = VL[(m * 36 + i) * 2 + 1];
        }
        float* Wp = ws + OFF_W + ((size_t)f * 36 + m * 6) * 2;
#pragma unroll
        for (int a = 0; a < 6; ++a) {
            w6[a][0] = Wp[2 * a]; w6[a][1] = Wp[2 * a + 1];
            wold[a][0] = w6[a][0]; wold[a][1] = w6[a][1];
            WL[(m * 6 + a) * 2] = w6[a][0]; WL[(m * 6 + a) * 2 + 1] = w6[a][1];
        }
    }
    __syncthreads();
    for (int k = 0; k < 6; ++k) {
        float wk[6][2];
        if (tid < 6) {
#pragma unroll
            for (int a = 0; a < 6; ++a) {
                wk[a][0] = WL[(k * 6 + a) * 2];
                wk[a][1] = WL[(k * 6 + a) * 2 + 1];
            }
        }
        __syncthreads();
        if (tid < 6) {
            float t6[6][2];
#pragma unroll
            for (int a = 0; a < 6; ++a) {
                float tr = 0.f, ti = 0.f;
#pragma unroll
                for (int b = 0; b < 6; ++b) {
                    float vr = vm[a * 6 + b][0], vi = vm[a * 6 + b][1];
                    tr += vr * wk[b][0] + vi * wk[b][1];
                    ti += vi * wk[b][0] - vr * wk[b][1];
                }
                t6[a][0] = tr; t6[a][1] = ti;
            }
            float quad = 0.f, nr = 0.f, ni = 0.f;
#pragma unroll
            for (int a = 0; a < 6; ++a) {
                quad += wk[a][0] * t6[a][0] - wk[a][1] * t6[a][1];
                nr   += w6[a][0] * t6[a][0] - w6[a][1] * t6[a][1];
                ni   += w6[a][0] * t6[a][1] + w6[a][1] * t6[a][0];
            }
            float denom = fmaxf(quad, 1e-10f);
            float vkr, vki;
            if (m == k) { vkr = 1.0f - 1.0f / sqrtf(denom); vki = 0.0f; }
            else { float inv = 1.0f / denom; vkr = nr * inv; vki = ni * inv; }
#pragma unroll
            for (int a = 0; a < 6; ++a) {
                w6[a][0] -= vkr * wk[a][0] - vki * wk[a][1];
                w6[a][1] -= vkr * wk[a][1] + vki * wk[a][0];
            }
#pragma unroll
            for (int a = 0; a < 6; ++a) {
                WL[(m * 6 + a) * 2]     = w6[a][0];
                WL[(m * 6 + a) * 2 + 1] = w6[a][1];
            }
        }
        __syncthreads();
    }
    float d2 = 0.f, o2 = 0.f;
    if (tid < 6) {
        float* Wp = ws + OFF_W + ((size_t)f * 36 + m * 6) * 2;
#pragma unroll
        for (int a = 0; a < 6; ++a) {
            Wp[2 * a] = w6[a][0]; Wp[2 * a + 1] = w6[a][1];
            float dr = w6[a][0] - wold[a][0], di = w6[a][1] - wold[a][1];
            d2 += dr * dr + di * di;
            o2 += wold[a][0] * wold[a][0] + wold[a][1] * wold[a][1];
        }
    }
#pragma unroll
    for (int d = 1; d < 8; d <<= 1) {
        d2 += __shfl_xor(d2, d);
        o2 += __shfl_xor(o2, d);
    }
    if (tid == 0) {
        pout[2 * bid]     = d2;
        pout[2 * bid + 1] = o2;
    }
}

// -------- final: out[k,t,f] = sum_m W[f,k,m] X[m,t,f], W cached in registers --------
__global__ __launch_bounds__(256) void finalY(const float2* __restrict__ X,
                                              const float* __restrict__ ws,
                                              float2* __restrict__ out) {
    const int f  = blockIdx.y * 256 + threadIdx.x;
    const int t0 = blockIdx.x * 32;
    if (f >= F_DIM) return;
    const float2* Wf = (const float2*)(ws + OFF_W) + (size_t)f * 36;
    float2 w[36];
#pragma unroll
    for (int i = 0; i < 36; ++i) w[i] = Wf[i];
    for (int tl = 0; tl < 32; ++tl) {
        int t = t0 + tl;
        float2 x[6];
#pragma unroll
        for (int m = 0; m < 6; ++m) x[m] = X[((size_t)m * T_DIM + t) * F_DIM + f];
#pragma unroll
        for (int k = 0; k < 6; ++k) {
            float yr = 0.f, yi = 0.f;
#pragma unroll
            for (int m = 0; m < 6; ++m) {
                float2 wk = w[k * 6 + m];
                yr += wk.x * x[m].x - wk.y * x[m].y;
                yi += wk.x * x[m].y + wk.y * x[m].x;
            }
            out[((size_t)k * T_DIM + t) * F_DIM + f] = make_float2(yr, yi);
        }
    }
}

extern "C" void kernel_launch(void* const* d_in, const int* in_sizes, int n_in,
                              void* d_out, int out_size, void* d_ws, size_t ws_size,
                              hipStream_t stream) {
    (void)in_sizes; (void)n_in; (void)out_size; (void)ws_size;
    const float2* X = (const float2*)d_in[0];
    float* ws = (float*)d_ws;
    float2* out = (float2*)d_out;
    float2* Xt = out;  // transposed X lives in d_out until finalY overwrites it

    transp<<<dim3(64, 17, 6), 256, 0, stream>>>(X, Xt, ws);
    for (int it = 0; it < N_ITER; ++it) {
        const float* pin = ws + (((it + 1) & 1) ? OFF_P1 : OFF_P0);
        float* pout      = ws + (((it    ) & 1) ? OFF_P1 : OFF_P0);
        passA<<<T_DIM / 8, 512, 0, stream>>>(X, ws, pin);
        passBC<<<F_DIM, 128, 0, stream>>>(Xt, ws, pin, pout);
    }
    finalY<<<dim3(T_DIM / 32, 3), 256, 0, stream>>>(X, ws, out);
}